// Round 4
// baseline (209.347 us; speedup 1.0000x reference)
//
#include <hip/hip_runtime.h>
#include <hip/hip_bf16.h>
#include <hip/hip_cooperative_groups.h>

namespace cg = cooperative_groups;

// NT-Xent loss: B=4096, D=128, TEMP=0.5, N2=8192.
// loss = mean_i [ log sum_{j!=i} exp(2*sim_ij) - 2*pos_i ]
// sim = zn zn^T (bf16 MFMA), pos_i = fp32 cosine(z_i, z_{i^B}).
// Self-diagonal handled by rowsum init = -exp(2*sim_ii_bf16).
//
// R4: R3's cooperative fusion returned out=0 (absmax 9.0 == loss value)
// -> hipLaunchCooperativeKernel was rejected (VGPR >128 => only 1 block/CU
// co-resident < 512 requested), error unchecked, kernel never ran.
// Fixes: __launch_bounds__(256,2) guarantees 2 blocks/CU (VGPR cap 128),
// and the launch error is checked with a fallback to the proven R0
// 3-kernel path (worst case = R0's 100 us, still correct).

#define BB 4096
#define N2 8192
#define DD 128
#define CSPLIT 16          // column splits
#define CW (N2 / CSPLIT)   // 512 cols per split
#define NCT (CW / 16)      // 32 col-tiles per split
#define NBLK 512           // 512 blocks = 2/CU (co-resident, cooperative-safe)

// 2*log2(e): exp(2x) = exp2(x * 2log2e)
#define C2LOG2E 2.8853900817779268f

#if __has_builtin(__builtin_amdgcn_exp2f)
#define EXP2F(x) __builtin_amdgcn_exp2f(x)
#else
#define EXP2F(x) __expf((x) * 0.6931471805599453f)
#endif

using bf16 = __hip_bfloat16;
typedef __attribute__((ext_vector_type(8))) short short8;   // MFMA A/B frag
typedef __attribute__((ext_vector_type(4))) float float4v;  // MFMA C/D frag

// ======================= fused cooperative kernel ==========================
__global__ __launch_bounds__(256, 2) void ntx_fused(
    const float* __restrict__ zi, const float* __restrict__ zj,
    bf16* __restrict__ zn, float* __restrict__ rowsum,
    float* __restrict__ pos, float* __restrict__ accum,
    unsigned int* __restrict__ cnt, float* __restrict__ out) {
  const int wave = threadIdx.x >> 6;
  const int lane = threadIdx.x & 63;

  // ---------------- Phase 1: per-pair normalize, cast bf16, pos, rowsum init
  if (blockIdx.x == 0 && threadIdx.x == 0) {
    atomicExch(accum, 0.0f);        // re-zeroed every replay
    atomicExch(cnt, 0u);
  }
  #pragma unroll
  for (int it = 0; it < 2; ++it) {
    const int pair = blockIdx.x * 8 + wave * 2 + it;   // 512*8 = 4096 pairs
    float2 v = ((const float2*)(zi + (size_t)pair * DD))[lane];
    float2 w = ((const float2*)(zj + (size_t)pair * DD))[lane];
    float s1 = v.x * v.x + v.y * v.y;   // |zi|^2
    float s2 = w.x * w.x + w.y * w.y;   // |zj|^2
    float s3 = v.x * w.x + v.y * w.y;   // zi . zj
    #pragma unroll
    for (int o = 32; o > 0; o >>= 1) {
      s1 += __shfl_xor(s1, o);
      s2 += __shfl_xor(s2, o);
      s3 += __shfl_xor(s3, o);
    }
    float nv = fmaxf(sqrtf(s1), 1e-8f);
    float nw = fmaxf(sqrtf(s2), 1e-8f);
    float rv = 1.0f / nv, rw = 1.0f / nw;
    bf16 bx = __float2bfloat16(v.x * rv);
    bf16 by = __float2bfloat16(v.y * rv);
    bf16 cx = __float2bfloat16(w.x * rw);
    bf16 cy = __float2bfloat16(w.y * rw);
    __hip_bfloat162 h2; h2.x = bx; h2.y = by;
    __hip_bfloat162 g2; g2.x = cx; g2.y = cy;
    ((__hip_bfloat162*)(zn + (size_t)pair * DD))[lane] = h2;
    ((__hip_bfloat162*)(zn + (size_t)(pair + BB) * DD))[lane] = g2;
    // self-similarity in the SAME precision the MFMA will see (bf16 rounded)
    float fx = __bfloat162float(bx), fy = __bfloat162float(by);
    float gx = __bfloat162float(cx), gy = __bfloat162float(cy);
    float sii = fx * fx + fy * fy;
    float sjj = gx * gx + gy * gy;
    #pragma unroll
    for (int o = 32; o > 0; o >>= 1) {
      sii += __shfl_xor(sii, o);
      sjj += __shfl_xor(sjj, o);
    }
    if (lane == 0) {
      float c = s3 / (nv * nw);            // fp32 positive-pair cosine
      // atomic writes -> coherent point; later phases read cross-XCD safely
      atomicExch(&rowsum[pair],      -EXP2F(sii * C2LOG2E));
      atomicExch(&rowsum[pair + BB], -EXP2F(sjj * C2LOG2E));
      atomicExch(&pos[pair],      c);
      atomicExch(&pos[pair + BB], c);
    }
  }

  cg::this_grid().sync();   // zn fully written + visible

  // ---------------- Phase 2: fused sim + sum-exp (R0 body) ----------------
  // block -> (colsplit, rowgroup): cs = x & 15, rb = x >> 4 (== R0 grid(16,32))
  {
    const int quad = lane >> 4;
    const int l15  = lane & 15;
    const short* zs = (const short*)zn;

    const int rowBase  = (blockIdx.x >> 4) * 256 + wave * 64;
    const int colBase0 = (blockIdx.x & 15) * CW;

    // A fragments: 4 row-tiles x 4 K-chunks (64 VGPRs)
    short8 a[4][4];
    #pragma unroll
    for (int t = 0; t < 4; t++) {
      const short* ap = zs + (size_t)(rowBase + t * 16 + l15) * DD + quad * 8;
      #pragma unroll
      for (int c = 0; c < 4; c++) a[t][c] = *(const short8*)(ap + c * 32);
    }

    float rs[4][4];
    #pragma unroll
    for (int t = 0; t < 4; t++)
      #pragma unroll
      for (int r = 0; r < 4; r++) rs[t][r] = 0.0f;

    const short* bbase = zs + (size_t)(colBase0 + l15) * DD + quad * 8;

    short8 b[4];
    #pragma unroll
    for (int c = 0; c < 4; c++) b[c] = *(const short8*)(bbase + c * 32);

    #pragma unroll 1
    for (int ct = 0; ct < NCT; ct++) {
      // prefetch next B tile (wraps to tile 0 on last iter — harmless)
      const int nct = (ct + 1) & (NCT - 1);
      const short* bp = bbase + (size_t)nct * 16 * DD;
      short8 bn[4];
      #pragma unroll
      for (int c = 0; c < 4; c++) bn[c] = *(const short8*)(bp + c * 32);

      #pragma unroll
      for (int t = 0; t < 4; t++) {
        float4v acc = {0.f, 0.f, 0.f, 0.f};
        acc = __builtin_amdgcn_mfma_f32_16x16x32_bf16(a[t][0], b[0], acc, 0, 0, 0);
        acc = __builtin_amdgcn_mfma_f32_16x16x32_bf16(a[t][1], b[1], acc, 0, 0, 0);
        acc = __builtin_amdgcn_mfma_f32_16x16x32_bf16(a[t][2], b[2], acc, 0, 0, 0);
        acc = __builtin_amdgcn_mfma_f32_16x16x32_bf16(a[t][3], b[3], acc, 0, 0, 0);
        // C/D: col = l15, row = quad*4 + r [m89/m91]; diagonal included,
        // cancelled by rowsum init.
        #pragma unroll
        for (int r = 0; r < 4; r++) rs[t][r] += EXP2F(acc[r] * C2LOG2E);
      }

      #pragma unroll
      for (int c = 0; c < 4; c++) b[c] = bn[c];
    }

    // reduce across the 16 lanes sharing each row, then one atomic each
    #pragma unroll
    for (int t = 0; t < 4; t++) {
      #pragma unroll
      for (int r = 0; r < 4; r++) {
        float s = rs[t][r];
        s += __shfl_xor(s, 1);
        s += __shfl_xor(s, 2);
        s += __shfl_xor(s, 4);
        s += __shfl_xor(s, 8);
        if (l15 == 0)
          atomicAdd(&rowsum[rowBase + t * 16 + quad * 4 + r], s);
      }
    }
  }

  cg::this_grid().sync();   // all rowsum atomics done

  // ---------------- Phase 3: finalize — each block owns 16 rows ------------
  {
    float v = 0.0f;
    if (threadIdx.x < 16) {
      const int r = blockIdx.x * 16 + threadIdx.x;
      // atomic reads: fetch from the coherent point regardless of XCD
      float rsv  = atomicAdd(&rowsum[r], 0.0f);
      float posv = atomicAdd(&pos[r], 0.0f);
      v = __logf(rsv) - 2.0f * posv;
    }
    if (wave == 0) {
      v += __shfl_xor(v, 1);
      v += __shfl_xor(v, 2);
      v += __shfl_xor(v, 4);
      v += __shfl_xor(v, 8);
      if (threadIdx.x == 0) {
        atomicAdd(accum, v);
        __threadfence();
        unsigned int old = atomicAdd(cnt, 1u);
        if (old == NBLK - 1) {              // last block finalizes
          out[0] = atomicAdd(accum, 0.0f) / (float)N2;
        }
      }
    }
  }
}

// ======================= fallback path (R0 3-kernel) =======================
__global__ __launch_bounds__(256) void ntx_norm_kernel(
    const float* __restrict__ zi, const float* __restrict__ zj,
    bf16* __restrict__ zn, float* __restrict__ rowsum, float* __restrict__ pos) {
  const int wave = threadIdx.x >> 6;
  const int lane = threadIdx.x & 63;
  const int pair = blockIdx.x * 4 + wave;   // 1024 blocks, 4 pairs/block
  float2 v = ((const float2*)(zi + (size_t)pair * DD))[lane];
  float2 w = ((const float2*)(zj + (size_t)pair * DD))[lane];
  float s1 = v.x * v.x + v.y * v.y;
  float s2 = w.x * w.x + w.y * w.y;
  float s3 = v.x * w.x + v.y * w.y;
  #pragma unroll
  for (int o = 32; o > 0; o >>= 1) {
    s1 += __shfl_xor(s1, o);
    s2 += __shfl_xor(s2, o);
    s3 += __shfl_xor(s3, o);
  }
  float nv = fmaxf(sqrtf(s1), 1e-8f);
  float nw = fmaxf(sqrtf(s2), 1e-8f);
  float rv = 1.0f / nv, rw = 1.0f / nw;
  bf16 bx = __float2bfloat16(v.x * rv);
  bf16 by = __float2bfloat16(v.y * rv);
  bf16 cx = __float2bfloat16(w.x * rw);
  bf16 cy = __float2bfloat16(w.y * rw);
  __hip_bfloat162 h2; h2.x = bx; h2.y = by;
  __hip_bfloat162 g2; g2.x = cx; g2.y = cy;
  ((__hip_bfloat162*)(zn + (size_t)pair * DD))[lane] = h2;
  ((__hip_bfloat162*)(zn + (size_t)(pair + BB) * DD))[lane] = g2;
  float fx = __bfloat162float(bx), fy = __bfloat162float(by);
  float gx = __bfloat162float(cx), gy = __bfloat162float(cy);
  float sii = fx * fx + fy * fy;
  float sjj = gx * gx + gy * gy;
  #pragma unroll
  for (int o = 32; o > 0; o >>= 1) {
    sii += __shfl_xor(sii, o);
    sjj += __shfl_xor(sjj, o);
  }
  if (lane == 0) {
    float c = s3 / (nv * nw);
    rowsum[pair]      = -EXP2F(sii * C2LOG2E);
    rowsum[pair + BB] = -EXP2F(sjj * C2LOG2E);
    pos[pair]      = c;
    pos[pair + BB] = c;
  }
}

__global__ __launch_bounds__(256) void ntx_sim_kernel(
    const bf16* __restrict__ zn, float* __restrict__ rowsum) {
  const int wave = threadIdx.x >> 6;
  const int lane = threadIdx.x & 63;
  const int quad = lane >> 4;
  const int l15  = lane & 15;
  const short* zs = (const short*)zn;

  const int rowBase = blockIdx.y * 256 + wave * 64;
  const int colBase0 = blockIdx.x * CW;

  short8 a[4][4];
  #pragma unroll
  for (int t = 0; t < 4; t++) {
    const short* ap = zs + (size_t)(rowBase + t * 16 + l15) * DD + quad * 8;
    #pragma unroll
    for (int c = 0; c < 4; c++) a[t][c] = *(const short8*)(ap + c * 32);
  }

  float rs[4][4];
  #pragma unroll
  for (int t = 0; t < 4; t++)
    #pragma unroll
    for (int r = 0; r < 4; r++) rs[t][r] = 0.0f;

  const short* bbase = zs + (size_t)(colBase0 + l15) * DD + quad * 8;

  short8 b[4];
  #pragma unroll
  for (int c = 0; c < 4; c++) b[c] = *(const short8*)(bbase + c * 32);

  #pragma unroll 1
  for (int ct = 0; ct < NCT; ct++) {
    const int nct = (ct + 1) & (NCT - 1);
    const short* bp = bbase + (size_t)nct * 16 * DD;
    short8 bn[4];
    #pragma unroll
    for (int c = 0; c < 4; c++) bn[c] = *(const short8*)(bp + c * 32);

    #pragma unroll
    for (int t = 0; t < 4; t++) {
      float4v acc = {0.f, 0.f, 0.f, 0.f};
      acc = __builtin_amdgcn_mfma_f32_16x16x32_bf16(a[t][0], b[0], acc, 0, 0, 0);
      acc = __builtin_amdgcn_mfma_f32_16x16x32_bf16(a[t][1], b[1], acc, 0, 0, 0);
      acc = __builtin_amdgcn_mfma_f32_16x16x32_bf16(a[t][2], b[2], acc, 0, 0, 0);
      acc = __builtin_amdgcn_mfma_f32_16x16x32_bf16(a[t][3], b[3], acc, 0, 0, 0);
      #pragma unroll
      for (int r = 0; r < 4; r++) rs[t][r] += EXP2F(acc[r] * C2LOG2E);
    }

    #pragma unroll
    for (int c = 0; c < 4; c++) b[c] = bn[c];
  }

  #pragma unroll
  for (int t = 0; t < 4; t++) {
    #pragma unroll
    for (int r = 0; r < 4; r++) {
      float s = rs[t][r];
      s += __shfl_xor(s, 1);
      s += __shfl_xor(s, 2);
      s += __shfl_xor(s, 4);
      s += __shfl_xor(s, 8);
      if (l15 == 0)
        atomicAdd(&rowsum[rowBase + t * 16 + quad * 4 + r], s);
    }
  }
}

__global__ __launch_bounds__(1024) void ntx_finalize_kernel(
    const float* __restrict__ rowsum, const float* __restrict__ pos,
    float* __restrict__ out) {
  float s = 0.f;
  for (int i = threadIdx.x; i < N2; i += 1024)
    s += __logf(rowsum[i]) - 2.0f * pos[i];
  #pragma unroll
  for (int o = 32; o > 0; o >>= 1) s += __shfl_xor(s, o);
  __shared__ float sm[16];
  const int wave = threadIdx.x >> 6;
  const int lane = threadIdx.x & 63;
  if (lane == 0) sm[wave] = s;
  __syncthreads();
  if (threadIdx.x == 0) {
    float t = 0.f;
    #pragma unroll
    for (int i = 0; i < 16; i++) t += sm[i];
    out[0] = t / (float)N2;
  }
}

extern "C" void kernel_launch(void* const* d_in, const int* in_sizes, int n_in,
                              void* d_out, int out_size, void* d_ws, size_t ws_size,
                              hipStream_t stream) {
  const float* zi = (const float*)d_in[0];
  const float* zj = (const float*)d_in[1];
  float* out = (float*)d_out;

  char* ws = (char*)d_ws;
  bf16* zn = (bf16*)ws;                                   // 8192*128*2 = 2 MB
  float* rowsum = (float*)(ws + (size_t)N2 * DD * 2);     // 32 KB
  float* pos = rowsum + N2;                               // 32 KB
  float* accum = pos + N2;                                // 4 B
  unsigned int* cnt = (unsigned int*)(accum + 1);         // 4 B

  void* args[] = {(void*)&zi, (void*)&zj, (void*)&zn, (void*)&rowsum,
                  (void*)&pos, (void*)&accum, (void*)&cnt, (void*)&out};
  hipError_t err = hipLaunchCooperativeKernel((void*)ntx_fused, dim3(NBLK),
                                              dim3(256), args, 0, stream);
  if (err != hipSuccess) {
    // Fallback: proven 3-kernel path (R0 structure), correct if slower.
    ntx_norm_kernel<<<BB / 4, 256, 0, stream>>>(zi, zj, zn, rowsum, pos);
    dim3 grid(CSPLIT, N2 / 256);
    ntx_sim_kernel<<<grid, 256, 0, stream>>>(zn, rowsum);
    ntx_finalize_kernel<<<1, 1024, 0, stream>>>(rowsum, pos, out);
  }
}

// Round 5
// 91.075 us; speedup vs baseline: 2.2986x; 2.2986x over previous
//
#include <hip/hip_runtime.h>
#include <hip/hip_bf16.h>

// NT-Xent loss: B=4096, D=128, TEMP=0.5, N2=8192.
// loss = mean_i [ log sum_{j!=i} exp(2*sim_ij) - 2*pos_i ]
// sim = zn zn^T (bf16 MFMA), pos_i = fp32 cosine(z_i, z_{i^B}).
// Self-diagonal handled by rowsum init = -exp(2*sim_ii_bf16).
//
// R5: back to 3 kernels (R4 proved the ~56us non-sim time is FIXED harness
// overhead — fusion/coop-launch can't remove it; grid.sync costs ~50us).
// Sim kernel rebuilt around the real bottleneck: scattered per-lane
// fragment loads (16 line-probes/instr) saturating per-CU L1/TA request
// throughput (explains R2: 3x occupancy, 2x loads -> 2x slower).
// Now: B staged to LDS per block — coalesced 16B/thread loads issued EARLY
// (T14), ds_write late, double-buffered, XOR-swizzled (chunk ^= row&7) so
// ds_read_b128 fragment reads are conflict-free. CSPLIT 32 = 4 blocks/CU.

#define BB 4096
#define N2 8192
#define DD 128
#define CSPLIT 32          // column splits (grid.x)
#define CW (N2 / CSPLIT)   // 256 cols per block
#define TW 32              // cols staged per round (2 col-tiles, 8 KB)
#define NRD (CW / TW)      // 8 rounds

// 2*log2(e): exp(2x) = exp2(x * 2log2e)
#define C2LOG2E 2.8853900817779268f

#if __has_builtin(__builtin_amdgcn_exp2f)
#define EXP2F(x) __builtin_amdgcn_exp2f(x)
#else
#define EXP2F(x) __expf((x) * 0.6931471805599453f)
#endif

using bf16 = __hip_bfloat16;
typedef __attribute__((ext_vector_type(8))) short short8;   // MFMA A/B frag
typedef __attribute__((ext_vector_type(4))) float float4v;  // MFMA C/D frag

// ---------------- Kernel 1: per-pair normalize, cast bf16, pos, rowsum init
__global__ __launch_bounds__(256) void ntx_norm_kernel(
    const float* __restrict__ zi, const float* __restrict__ zj,
    bf16* __restrict__ zn, float* __restrict__ rowsum, float* __restrict__ pos) {
  const int wave = threadIdx.x >> 6;
  const int lane = threadIdx.x & 63;
  const int pair = blockIdx.x * 4 + wave;   // 1024 blocks, 4 pairs/block
  float2 v = ((const float2*)(zi + (size_t)pair * DD))[lane];
  float2 w = ((const float2*)(zj + (size_t)pair * DD))[lane];
  float s1 = v.x * v.x + v.y * v.y;
  float s2 = w.x * w.x + w.y * w.y;
  float s3 = v.x * w.x + v.y * w.y;
  #pragma unroll
  for (int o = 32; o > 0; o >>= 1) {
    s1 += __shfl_xor(s1, o);
    s2 += __shfl_xor(s2, o);
    s3 += __shfl_xor(s3, o);
  }
  float nv = fmaxf(sqrtf(s1), 1e-8f);
  float nw = fmaxf(sqrtf(s2), 1e-8f);
  float rv = 1.0f / nv, rw = 1.0f / nw;
  bf16 bx = __float2bfloat16(v.x * rv);
  bf16 by = __float2bfloat16(v.y * rv);
  bf16 cx = __float2bfloat16(w.x * rw);
  bf16 cy = __float2bfloat16(w.y * rw);
  __hip_bfloat162 h2; h2.x = bx; h2.y = by;
  __hip_bfloat162 g2; g2.x = cx; g2.y = cy;
  ((__hip_bfloat162*)(zn + (size_t)pair * DD))[lane] = h2;
  ((__hip_bfloat162*)(zn + (size_t)(pair + BB) * DD))[lane] = g2;
  // self-similarity in the SAME precision the MFMA will see (bf16 rounded)
  float fx = __bfloat162float(bx), fy = __bfloat162float(by);
  float gx = __bfloat162float(cx), gy = __bfloat162float(cy);
  float sii = fx * fx + fy * fy;
  float sjj = gx * gx + gy * gy;
  #pragma unroll
  for (int o = 32; o > 0; o >>= 1) {
    sii += __shfl_xor(sii, o);
    sjj += __shfl_xor(sjj, o);
  }
  if (lane == 0) {
    float c = s3 / (nv * nw);
    rowsum[pair]      = -EXP2F(sii * C2LOG2E);  // cancels diagonal term
    rowsum[pair + BB] = -EXP2F(sjj * C2LOG2E);
    pos[pair]      = c;
    pos[pair + BB] = c;
  }
}

// ---------------- Kernel 2: fused sim + sum-exp ----------------------------
// grid (CSPLIT=32, 32). Block 256 = 4 waves; wave owns 64 rows (4 row-tiles),
// block owns 256 rows x 256 cols. Per round: stage 32 cols (8 KB) of B into
// LDS (coalesced, swizzled source), each wave does 8 ds_read_b128 + 32 MFMA
// + 32 exp. Double-buffered; loads issued before compute, written after.
__global__ __launch_bounds__(256) void ntx_sim_kernel(
    const bf16* __restrict__ zn, float* __restrict__ rowsum) {
  const int tid  = threadIdx.x;
  const int wave = tid >> 6;
  const int lane = tid & 63;
  const int quad = lane >> 4;
  const int l15  = lane & 15;
  const char* zb  = (const char*)zn;
  const short* zs = (const short*)zn;

  __shared__ float4 lds[2][TW * 16];   // 2 x 8 KB double buffer

  const int rowBase  = blockIdx.y * 256 + wave * 64;
  const int colBase0 = blockIdx.x * CW;

  // A fragments: 4 row-tiles x 4 K-chunks (64 VGPRs) — loaded once
  short8 a[4][4];
  #pragma unroll
  for (int t = 0; t < 4; t++) {
    const short* ap = zs + (size_t)(rowBase + t * 16 + l15) * DD + quad * 8;
    #pragma unroll
    for (int c = 0; c < 4; c++) a[t][c] = *(const short8*)(ap + c * 32);
  }

  float rs[4][4];
  #pragma unroll
  for (int t = 0; t < 4; t++)
    #pragma unroll
    for (int r = 0; r < 4; r++) rs[t][r] = 0.0f;

  // Staging map: 512 chunks of 16B per round. Thread handles chunk tid and
  // tid+256. Chunk p: row = p>>4 (col-row within staged block), slot = p&15.
  // LDS[row][slot] holds global chunk (slot ^ (row&7)) of that row
  // -> ds_read with the same XOR is bank-conflict-free (2 lanes/bank).
  // Thread's 2nd chunk (p+256) is exactly +4096B in both src and dst.
  const int g0 = tid >> 4;
  const int sw = ((tid & 15) ^ (g0 & 7)) << 4;
  const char* srcb = zb + (size_t)(colBase0 + g0) * 256 + sw;

  // prologue: stage round 0
  {
    float4 t0 = *(const float4*)(srcb);
    float4 t1 = *(const float4*)(srcb + 4096);
    lds[0][tid] = t0;
    lds[0][tid + 256] = t1;
  }
  __syncthreads();

  int cur = 0;
  #pragma unroll 1
  for (int rd = 0; rd < NRD; rd++) {
    // issue next round's loads EARLY — L2 latency hides under compute
    float4 t0, t1;
    const bool pf = (rd + 1 < NRD);
    if (pf) {
      const char* sb = srcb + (size_t)(rd + 1) * (TW * 256);
      t0 = *(const float4*)(sb);
      t1 = *(const float4*)(sb + 4096);
    }

    const char* lb = (const char*)&lds[cur][0];
    #pragma unroll
    for (int k = 0; k < 2; k++) {           // 2 col-tiles per round
      short8 b[4];
      #pragma unroll
      for (int c = 0; c < 4; c++) {
        const int off = k * 4096 + l15 * 256 +
                        ((((c * 4 + quad) ^ (l15 & 7))) << 4);
        b[c] = *(const short8*)(lb + off);
      }
      #pragma unroll
      for (int t = 0; t < 4; t++) {
        float4v acc = {0.f, 0.f, 0.f, 0.f};
        acc = __builtin_amdgcn_mfma_f32_16x16x32_bf16(a[t][0], b[0], acc, 0, 0, 0);
        acc = __builtin_amdgcn_mfma_f32_16x16x32_bf16(a[t][1], b[1], acc, 0, 0, 0);
        acc = __builtin_amdgcn_mfma_f32_16x16x32_bf16(a[t][2], b[2], acc, 0, 0, 0);
        acc = __builtin_amdgcn_mfma_f32_16x16x32_bf16(a[t][3], b[3], acc, 0, 0, 0);
        // C/D: col = l15, row = quad*4 + r [m89/m91]; diagonal included,
        // cancelled by rowsum init.
        #pragma unroll
        for (int r = 0; r < 4; r++) rs[t][r] += EXP2F(acc[r] * C2LOG2E);
      }
    }

    if (pf) {
      __syncthreads();        // prior round's readers of buf[cur^1] done
      lds[cur ^ 1][tid] = t0;
      lds[cur ^ 1][tid + 256] = t1;
      __syncthreads();        // staged tile visible before next reads
      cur ^= 1;
    }
  }

  // reduce across the 16 lanes sharing each row, then one atomic each
  #pragma unroll
  for (int t = 0; t < 4; t++) {
    #pragma unroll
    for (int r = 0; r < 4; r++) {
      float s = rs[t][r];
      s += __shfl_xor(s, 1);
      s += __shfl_xor(s, 2);
      s += __shfl_xor(s, 4);
      s += __shfl_xor(s, 8);
      if (l15 == 0)
        atomicAdd(&rowsum[rowBase + t * 16 + quad * 4 + r], s);
    }
  }
}

// ---------------- Kernel 3: finalize --------------------------------------
__global__ __launch_bounds__(1024) void ntx_finalize_kernel(
    const float* __restrict__ rowsum, const float* __restrict__ pos,
    float* __restrict__ out) {
  float s = 0.f;
  for (int i = threadIdx.x; i < N2; i += 1024)
    s += __logf(rowsum[i]) - 2.0f * pos[i];
  #pragma unroll
  for (int o = 32; o > 0; o >>= 1) s += __shfl_xor(s, o);
  __shared__ float sm[16];
  const int wave = threadIdx.x >> 6;
  const int lane = threadIdx.x & 63;
  if (lane == 0) sm[wave] = s;
  __syncthreads();
  if (threadIdx.x == 0) {
    float t = 0.f;
    #pragma unroll
    for (int i = 0; i < 16; i++) t += sm[i];
    out[0] = t / (float)N2;
  }
}

extern "C" void kernel_launch(void* const* d_in, const int* in_sizes, int n_in,
                              void* d_out, int out_size, void* d_ws, size_t ws_size,
                              hipStream_t stream) {
  const float* zi = (const float*)d_in[0];
  const float* zj = (const float*)d_in[1];
  float* out = (float*)d_out;

  char* ws = (char*)d_ws;
  bf16* zn = (bf16*)ws;                                   // 8192*128*2 = 2 MB
  float* rowsum = (float*)(ws + (size_t)N2 * DD * 2);     // 32 KB
  float* pos = rowsum + N2;                               // 32 KB

  ntx_norm_kernel<<<BB / 4, 256, 0, stream>>>(zi, zj, zn, rowsum, pos);
  dim3 grid(CSPLIT, N2 / 256);
  ntx_sim_kernel<<<grid, 256, 0, stream>>>(zn, rowsum);
  ntx_finalize_kernel<<<1, 1024, 0, stream>>>(rowsum, pos, out);
}